// Round 3
// baseline (648.791 us; speedup 1.0000x reference)
//
#include <hip/hip_runtime.h>

#define DBITS 18

__device__ __forceinline__ int swz(int j){ return j ^ ((j >> 6) & 15); }

__device__ __forceinline__ unsigned pack_bf2(float r, float i){
  unsigned ur = __float_as_uint(r), ui = __float_as_uint(i);
  ur = (ur + 0x7FFFu + ((ur >> 16) & 1u)) >> 16;
  ui = (ui + 0x7FFFu + ((ui >> 16) & 1u)) & 0xFFFF0000u;
  return ur | ui;
}
__device__ __forceinline__ float2 unpack_bf2(unsigned u){
  return make_float2(__uint_as_float(u << 16), __uint_as_float(u & 0xFFFF0000u));
}

// SU(2) gate U = [[a, b], [-conj(b), conj(a)]], g = {ar, ai, br, bi}.
template<int S>
__device__ __forceinline__ void gate_reg(float ar[16], float ai[16], const float* __restrict__ g){
  const float Ar=g[0], Ai=g[1], Br=g[2], Bi=g[3];
  #pragma unroll
  for (int h = 0; h < 8; ++h){
    const int c0 = ((h & ~(S-1)) << 1) | (h & (S-1));
    const int c1 = c0 | S;
    const float x0r=ar[c0], x0i=ai[c0], x1r=ar[c1], x1i=ai[c1];
    ar[c0] =  Ar*x0r - Ai*x0i + Br*x1r - Bi*x1i;
    ai[c0] =  Ar*x0i + Ai*x0r + Br*x1i + Bi*x1r;
    ar[c1] = -Br*x0r - Bi*x0i + Ar*x1r + Ai*x1i;
    ai[c1] = -Br*x0i + Bi*x0r + Ar*x1i - Ai*x1r;
  }
}

template<int CTRL>
__device__ __forceinline__ float dppf(float v){
  return __int_as_float(__builtin_amdgcn_update_dpp(0, __float_as_int(v), CTRL, 0xF, 0xF, true));
}

// Gate on a lane bit: partner via DPP quad_perm (xor1: 0xB1, xor2: 0x4E).
// s = -1 for lanes with the bit set (SU(2) parity trick; derivation verified).
template<int CTRL>
__device__ __forceinline__ void gate_lane(float ar[16], float ai[16], const float* __restrict__ g, float s){
  const float uer = g[0], uei = s*g[1], uor = s*g[2], uoi = g[3];
  #pragma unroll
  for (int c = 0; c < 16; ++c){
    const float pr = dppf<CTRL>(ar[c]);
    const float pi = dppf<CTRL>(ai[c]);
    const float xr = ar[c], xi = ai[c];
    ar[c] = uer*xr - uei*xi + uor*pr - uoi*pi;
    ai[c] = uer*xi + uei*xr + uor*pi + uoi*pr;
  }
}

__host__ __device__ constexpr int gbit(int p, int SL, int SH){ return p < SL ? p : p - SL + SH; }

// Gate ledger (layer, wire) -> (pass, round); each applied exactly once:
//  L1: P1.R1 w7..4 | P1.dpp w17,16 | P1.R2 w15..12 | P1.R3 w11..8 | P2.R1 w3..0
//  sign1: P2.R1 (after L1 complete)
//  L2: P2.dpp w17,16 | P2.R2 w15..12 | P2.R3 w11..8 | P3.R1 w3..0 | P3.R2 w7..4
//  sign2: P3.R2 (after L2 complete)
//  L3: P3.dpp w17,16 | P3.R3 w15..12 | P4.R1 w3..0 | P4.R2 w11..8 | P4.R3 w7..4
//  final CZ layer: absorbed by |amp|^2 (diagonal signs)
template<int PASS>
__global__ __launch_bounds__(1024)
void qpass(const float* __restrict__ sr, const float* __restrict__ si,
           unsigned* __restrict__ st, const float* __restrict__ gates,
           const float* __restrict__ head_w, float* __restrict__ partials,
           int batch0)
{
  constexpr int SL = (PASS==1)?14:(PASS==2)?10:(PASS==3)?6:2;
  constexpr int SH = (PASS==1)?14:(PASS==2)?14:(PASS==3)?10:6;
  constexpr int ML = (1<<SL)-1;
  __shared__ float2 lds[16384];
  const int t = threadIdx.x;

  // XCD-aware bijective swizzle
  const int nwg = (int)gridDim.x;
  const int p = (int)blockIdx.x;
  const int q = nwg >> 3, r = nwg & 7, x = p & 7, m = p >> 3;
  const int logical = (x < r ? x*(q+1) : r*(q+1) + (x-r)*q) + m;
  const int f  = logical & 15;
  const int bl = logical >> 4;
  const int bg = batch0 + bl;
  const unsigned stBase = ((unsigned)bl) << DBITS;
  const size_t  inBase  = ((size_t)bg) << DBITS;

  float ar[16], ai[16];

  // ---- R1: global -> regs; register bits = j[10..13] ----
  {
    #pragma unroll
    for (int c = 0; c < 16; ++c){
      const int j = t | (c << 10);
      const int gg = ((j >> SL) << SH) | (f << SL) | (j & ML);
      if (PASS == 1){
        ar[c] = sr[inBase + (size_t)gg];
        ai[c] = si[inBase + (size_t)gg];
      } else {
        const float2 v = unpack_bf2(st[stBase + (unsigned)gg]);
        ar[c] = v.x; ai[c] = v.y;
      }
    }
    constexpr int LR1 = (PASS<=2)?0:(PASS==3)?1:2;
    gate_reg<1>(ar, ai, gates + (LR1*18 + 17 - gbit(10,SL,SH))*4);
    gate_reg<2>(ar, ai, gates + (LR1*18 + 17 - gbit(11,SL,SH))*4);
    gate_reg<4>(ar, ai, gates + (LR1*18 + 17 - gbit(12,SL,SH))*4);
    gate_reg<8>(ar, ai, gates + (LR1*18 + 17 - gbit(13,SL,SH))*4);
    if (PASS == 2){  // sign1: L1 now complete, before first L2 gates
      #pragma unroll
      for (int c = 0; c < 16; ++c){
        const int j = t | (c << 10);
        const int gg = ((j >> SL) << SH) | (f << SL) | (j & ML);
        const unsigned sb = (unsigned)(__popc(gg & (gg >> 1)) & 1) << 31;
        ar[c] = __uint_as_float(__float_as_uint(ar[c]) ^ sb);
        ai[c] = __uint_as_float(__float_as_uint(ai[c]) ^ sb);
      }
    }
    if (PASS <= 2){  // DPP gates on local bits 0,1 (wires 17,16): P1->L1, P2->L2
      constexpr int LD = (PASS==1)?0:1;
      const float s1 = (t & 1) ? -1.f : 1.f;
      const float s2 = (t & 2) ? -1.f : 1.f;
      gate_lane<0xB1>(ar, ai, gates + (LD*18 + 17)*4, s1);
      gate_lane<0x4E>(ar, ai, gates + (LD*18 + 16)*4, s2);
    }
    const int sjb = swz(t);
    #pragma unroll
    for (int c = 0; c < 16; ++c) lds[sjb ^ (c << 10)] = make_float2(ar[c], ai[c]);
  }
  __syncthreads();

  // ---- R2 ----
  if (PASS != 3){
    // register bits = j[2..5]
    const int jb = (t & 3) | ((t >> 2) << 6);
    const int sjb = swz(jb);
    #pragma unroll
    for (int c = 0; c < 16; ++c){
      const float2 v = lds[sjb ^ (c << 2)];
      ar[c] = v.x; ai[c] = v.y;
    }
    constexpr int LR2 = (PASS==1)?0:(PASS==4)?2:1;
    gate_reg<1>(ar, ai, gates + (LR2*18 + 17 - gbit(2,SL,SH))*4);
    gate_reg<2>(ar, ai, gates + (LR2*18 + 17 - gbit(3,SL,SH))*4);
    gate_reg<4>(ar, ai, gates + (LR2*18 + 17 - gbit(4,SL,SH))*4);
    gate_reg<8>(ar, ai, gates + (LR2*18 + 17 - gbit(5,SL,SH))*4);
    #pragma unroll
    for (int c = 0; c < 16; ++c) lds[sjb ^ (c << 2)] = make_float2(ar[c], ai[c]);
  } else {
    // PASS 3: register bits = j[6..9] — finish L2 (w7..4), sign2, DPP L3 (w17,16)
    const int jb = (t & 63) | ((t >> 6) << 10);
    #pragma unroll
    for (int c = 0; c < 16; ++c){
      const float2 v = lds[jb ^ ((c << 6) ^ c)];
      ar[c] = v.x; ai[c] = v.y;
    }
    gate_reg<1>(ar, ai, gates + (1*18 + 17 - gbit(6,SL,SH))*4);   // w7
    gate_reg<2>(ar, ai, gates + (1*18 + 17 - gbit(7,SL,SH))*4);   // w6
    gate_reg<4>(ar, ai, gates + (1*18 + 17 - gbit(8,SL,SH))*4);   // w5
    gate_reg<8>(ar, ai, gates + (1*18 + 17 - gbit(9,SL,SH))*4);   // w4
    #pragma unroll
    for (int c = 0; c < 16; ++c){  // sign2: L2 now complete
      const int j = jb | (c << 6);
      const int gg = ((j >> SL) << SH) | (f << SL) | (j & ML);
      const unsigned sb = (unsigned)(__popc(gg & (gg >> 1)) & 1) << 31;
      ar[c] = __uint_as_float(__float_as_uint(ar[c]) ^ sb);
      ai[c] = __uint_as_float(__float_as_uint(ai[c]) ^ sb);
    }
    const float s1 = (t & 1) ? -1.f : 1.f;
    const float s2 = (t & 2) ? -1.f : 1.f;
    gate_lane<0xB1>(ar, ai, gates + (2*18 + 17)*4, s1);
    gate_lane<0x4E>(ar, ai, gates + (2*18 + 16)*4, s2);
    #pragma unroll
    for (int c = 0; c < 16; ++c) lds[jb ^ ((c << 6) ^ c)] = make_float2(ar[c], ai[c]);
  }
  __syncthreads();

  // ---- R3 ----
  if (PASS == 3){
    // register bits = j[2..5]: L3 w15..12, bf16 store
    const int jb = (t & 3) | ((t >> 2) << 6);
    const int sjb = swz(jb);
    #pragma unroll
    for (int c = 0; c < 16; ++c){
      const float2 v = lds[sjb ^ (c << 2)];
      ar[c] = v.x; ai[c] = v.y;
    }
    gate_reg<1>(ar, ai, gates + (2*18 + 17 - gbit(2,SL,SH))*4);   // w15
    gate_reg<2>(ar, ai, gates + (2*18 + 17 - gbit(3,SL,SH))*4);   // w14
    gate_reg<4>(ar, ai, gates + (2*18 + 17 - gbit(4,SL,SH))*4);   // w13
    gate_reg<8>(ar, ai, gates + (2*18 + 17 - gbit(5,SL,SH))*4);   // w12
    #pragma unroll
    for (int c = 0; c < 16; ++c){
      const int j = jb | (c << 2);
      const int gg = ((j >> SL) << SH) | (f << SL) | (j & ML);
      st[stBase + (unsigned)gg] = pack_bf2(ar[c], ai[c]);
    }
  } else {
    // register bits = j[6..9]
    const int jb = (t & 63) | ((t >> 6) << 10);
    #pragma unroll
    for (int c = 0; c < 16; ++c){
      const float2 v = lds[jb ^ ((c << 6) ^ c)];
      ar[c] = v.x; ai[c] = v.y;
    }
    constexpr int LR3 = (PASS==1)?0:(PASS==2)?1:2;
    gate_reg<1>(ar, ai, gates + (LR3*18 + 17 - gbit(6,SL,SH))*4);
    gate_reg<2>(ar, ai, gates + (LR3*18 + 17 - gbit(7,SL,SH))*4);
    gate_reg<4>(ar, ai, gates + (LR3*18 + 17 - gbit(8,SL,SH))*4);
    gate_reg<8>(ar, ai, gates + (LR3*18 + 17 - gbit(9,SL,SH))*4);
    if (PASS <= 2){
      #pragma unroll
      for (int c = 0; c < 16; ++c){
        const int j = jb | (c << 6);
        const int gg = ((j >> SL) << SH) | (f << SL) | (j & ML);
        st[stBase + (unsigned)gg] = pack_bf2(ar[c], ai[c]);
      }
    } else {
      // PASS 4: fused head
      const int gg0 = ((jb >> SL) << SH) | (f << SL) | (jb & ML);
      float cb = 0.f;
      #pragma unroll
      for (int k = 0; k < 18; ++k){
        const float hw = head_w[17-k];
        cb += ((gg0 >> k) & 1) ? -hw : hw;
      }
      // c bit m -> j bit 6+m -> global bit 10+m -> wire 7-m
      const float d0 = -2.f*head_w[7], d1 = -2.f*head_w[6];
      const float d2 = -2.f*head_w[5], d3 = -2.f*head_w[4];
      float acc = 0.f;
      #pragma unroll
      for (int c = 0; c < 16; ++c){
        float coef = cb;
        if (c & 1) coef += d0;
        if (c & 2) coef += d1;
        if (c & 4) coef += d2;
        if (c & 8) coef += d3;
        acc += coef * (ar[c]*ar[c] + ai[c]*ai[c]);
      }
      __syncthreads();   // all LDS reads done; reuse LDS for reduction
      #pragma unroll
      for (int off = 32; off; off >>= 1) acc += __shfl_down(acc, off);
      float* red = reinterpret_cast<float*>(lds);
      if ((t & 63) == 0) red[t >> 6] = acc;
      __syncthreads();
      if (t == 0){
        float s = 0.f;
        #pragma unroll
        for (int i = 0; i < 16; ++i) s += red[i];
        partials[bg * 16 + f] = s;
      }
    }
  }
}

__global__ void qprep(const float* __restrict__ params, float* __restrict__ gates){
  const int tid = threadIdx.x;
  if (tid < 54){
    const float xx = params[tid*3+0]*0.5f, yy = params[tid*3+1]*0.5f, zz = params[tid*3+2]*0.5f;
    float sx,cx,sy,cy,sz,cz;
    sincosf(xx,&sx,&cx); sincosf(yy,&sy,&cy); sincosf(zz,&sz,&cz);
    float* gp = gates + tid*4;
    gp[0] =  cz*cy*cx + sz*sy*sx;   // a_r  (u00)
    gp[1] =  cz*sy*sx - sz*cy*cx;   // a_i
    gp[2] = -cz*sy*cx - sz*cy*sx;   // b_r  (u01)
    gp[3] =  sz*sy*cx - cz*cy*sx;   // b_i
  }
}

__global__ void qfinal(const float* __restrict__ partials, const float* __restrict__ head_b,
                       float* __restrict__ out, int B){
  const int b = threadIdx.x + blockIdx.x * blockDim.x;
  if (b < B){
    float s = head_b[0];
    #pragma unroll
    for (int i = 0; i < 16; ++i) s += partials[b*16 + i];
    out[b] = s;
  }
}

extern "C" void kernel_launch(void* const* d_in, const int* in_sizes, int n_in,
                              void* d_out, int out_size, void* d_ws, size_t ws_size,
                              hipStream_t stream){
  const float* sr     = (const float*)d_in[0];
  const float* si     = (const float*)d_in[1];
  const float* params = (const float*)d_in[2];
  const float* head_w = (const float*)d_in[3];
  const float* head_b = (const float*)d_in[4];
  float* out = (float*)d_out;
  const int B = in_sizes[0] >> DBITS;   // 128

  float*    gates    = (float*)d_ws;                       // 54*4 floats
  float*    partials = (float*)d_ws + 512;                 // [2048,10240) bytes
  unsigned* st       = (unsigned*)((char*)d_ws + 16384);   // bf16-packed state chunk

  size_t stBytes = ws_size > 16384 ? ws_size - 16384 : 0;
  int maxChunk = (int)(stBytes / ((size_t)(1 << DBITS) * 4));
  if (maxChunk > B) maxChunk = B;
  if (maxChunk < 1) maxChunk = 1;

  qprep<<<dim3(1), dim3(64), 0, stream>>>(params, gates);

  for (int b0 = 0; b0 < B; b0 += maxChunk){
    const int c = (B - b0 < maxChunk) ? (B - b0) : maxChunk;
    dim3 grid(c * 16), blk(1024);
    qpass<1><<<grid, blk, 0, stream>>>(sr, si, st, gates, head_w, partials, b0);
    qpass<2><<<grid, blk, 0, stream>>>(sr, si, st, gates, head_w, partials, b0);
    qpass<3><<<grid, blk, 0, stream>>>(sr, si, st, gates, head_w, partials, b0);
    qpass<4><<<grid, blk, 0, stream>>>(sr, si, st, gates, head_w, partials, b0);
  }
  qfinal<<<dim3(1), dim3(128), 0, stream>>>(partials, head_b, out, B);
}